// Round 1
// baseline (7558.132 us; speedup 1.0000x reference)
//
#include <hip/hip_runtime.h>

#define DT 0.042f
constexpr int B = 64, L = 1024, I = 128, H = 512;

// ---------------------------------------------------------------------------
// Kernel 1: u = x @ x2h + bias  -> written into the all_states region of d_out
// x viewed as (B*L, I) = (65536, 128); x2h (128, 512). Tile 64x64, K=128 full.
// ---------------------------------------------------------------------------
__global__ __launch_bounds__(256) void k_ugemm(const float* __restrict__ x,
                                               const float* __restrict__ w,
                                               const float* __restrict__ bias,
                                               float* __restrict__ u) {
    __shared__ __align__(16) float a_s[64][132];   // pad 132: conflict-free, 16B rows
    __shared__ __align__(16) float b_s[128][68];   // pad 68: 272B rows, 16B aligned
    const int tx = threadIdx.x & 15;
    const int ty = threadIdx.x >> 4;
    const int row0 = blockIdx.x * 64;
    const int col0 = blockIdx.y * 64;

    for (int i = threadIdx.x; i < 64 * 32; i += 256) {       // 2048 float4 of x
        int r = i >> 5, c4 = (i & 31) << 2;
        *(float4*)&a_s[r][c4] = *(const float4*)(x + (size_t)(row0 + r) * I + c4);
    }
    for (int i = threadIdx.x; i < 128 * 16; i += 256) {      // 2048 float4 of w
        int k = i >> 4, c4 = (i & 15) << 2;
        *(float4*)&b_s[k][c4] = *(const float4*)(w + (size_t)k * H + col0 + c4);
    }
    __syncthreads();

    float acc[4][4] = {};
    for (int k = 0; k < I; k += 4) {
        float a4[4][4], b4[4][4];
        #pragma unroll
        for (int i = 0; i < 4; ++i) *(float4*)a4[i] = *(const float4*)&a_s[ty * 4 + i][k];
        #pragma unroll
        for (int kk = 0; kk < 4; ++kk) *(float4*)b4[kk] = *(const float4*)&b_s[k + kk][tx * 4];
        #pragma unroll
        for (int i = 0; i < 4; ++i)
            #pragma unroll
            for (int kk = 0; kk < 4; ++kk)
                #pragma unroll
                for (int j = 0; j < 4; ++j)
                    acc[i][j] += a4[i][kk] * b4[kk][j];
    }
    float4 bv = *(const float4*)&bias[col0 + tx * 4];
    #pragma unroll
    for (int i = 0; i < 4; ++i) {
        size_t r = (size_t)(row0 + ty * 4 + i);
        float4 o;
        o.x = acc[i][0] + bv.x; o.y = acc[i][1] + bv.y;
        o.z = acc[i][2] + bv.z; o.w = acc[i][3] + bv.w;
        *(float4*)&u[r * H + col0 + tx * 4] = o;
    }
}

// ---------------------------------------------------------------------------
// Kernel 2: the scan. 8 groups (8 batches each) x 8 slice-blocks (64 cols each).
// h2h column-slice LDS-resident (128 KiB). Per step: one group barrier
// (monotonic counter, agent scope), hy exchange via agent-scope atomics in d_ws
// (double-buffered), register-tiled partial matmul, LDS k-reduction, update.
// States (hy,hz) live in registers: thread (sb,scc) owns one (batch, col).
// u is read in-place from d_out and overwritten with the state output.
// ---------------------------------------------------------------------------
__global__ __launch_bounds__(512) void k_scan(float* __restrict__ su,
                                              const float* __restrict__ h2h,
                                              const float* __restrict__ gamma,
                                              const float* __restrict__ epsv,
                                              unsigned* __restrict__ ctr,
                                              float* __restrict__ wshy,
                                              float* __restrict__ hyfin) {
    __shared__ __align__(16) float h2h_s[H][64];   // [k][cc]  128 KiB
    __shared__ __align__(16) float xch[8 * H];     // 16 KiB: hy_s[b][k], then red[kc][b*64+cc]
    const int tid = threadIdx.x;
    const int g = blockIdx.x & 7;    // group (likely same-XCD members: perf heuristic only)
    const int s = blockIdx.x >> 3;   // column-slice id
    const int b0 = g * 8, c0 = s * 64;

    for (int i = tid; i < H * 16; i += 512) {      // load h2h slice, float4
        int k = i >> 4, c4 = (i & 15) << 2;
        *(float4*)&h2h_s[k][c4] = *(const float4*)(h2h + (size_t)k * H + c0 + c4);
    }

    // state mapping: one (batch, col) per thread
    const int sb = tid >> 6, scc = tid & 63;
    const int sc = c0 + scc;
    const float gam = gamma[sc], ep = epsv[sc];
    // compute mapping: (col, k-chunk)
    const int cc = tid & 63, kc = tid >> 6;

    float hy = 0.f, hz = 0.f;
    float* su_p = su + ((size_t)(b0 + sb) * L) * H + sc;
    unsigned* myctr = ctr + g * 32;  // 128B-strided counters: no false sharing
    __syncthreads();

    for (int t = 0; t < L; ++t) {
        // --- 1. wait until all group members published hy_t, then load it ---
        if (t > 0) {
            if (tid == 0) {
                const unsigned target = 8u * (unsigned)t;
                while (__hip_atomic_load(myctr, __ATOMIC_ACQUIRE,
                                         __HIP_MEMORY_SCOPE_AGENT) < target) {}
            }
            __syncthreads();
            const float* src = wshy + ((t & 1) ? (size_t)(B * H) : 0) + (size_t)b0 * H;
            #pragma unroll
            for (int j = 0; j < 8; ++j) {
                const int idx = tid + j * 512;     // xch[b][k] layout == src layout
                xch[idx] = __hip_atomic_load(&src[idx], __ATOMIC_RELAXED,
                                             __HIP_MEMORY_SCOPE_AGENT);
            }
        } else {
            #pragma unroll
            for (int j = 0; j < 8; ++j) xch[tid + j * 512] = 0.f;  // hy_0 = 0
        }
        __syncthreads();

        // --- 2. partial matmul: acc[b] = sum_{k in own chunk} hy[b][k]*h2h[k][c] ---
        float acc[8] = {};
        for (int kk = 0; kk < 64; kk += 4) {
            const int k = kc * 64 + kk;
            const float h0 = h2h_s[k][cc],     h1 = h2h_s[k + 1][cc];
            const float h2v = h2h_s[k + 2][cc], h3 = h2h_s[k + 3][cc];
            #pragma unroll
            for (int b = 0; b < 8; ++b) {
                const float4 hv = *(const float4*)&xch[b * H + k];  // wave-uniform broadcast
                acc[b] += hv.x * h0 + hv.y * h1 + hv.z * h2v + hv.w * h3;
            }
        }
        __syncthreads();                       // done reading hy_s: safe to alias as red
        #pragma unroll
        for (int b = 0; b < 8; ++b) xch[kc * 512 + b * 64 + cc] = acc[b];
        __syncthreads();

        // --- 3. k-reduction + elementwise update (state mapping) ---
        float mm = 0.f;
        #pragma unroll
        for (int q = 0; q < 8; ++q) mm += xch[q * 512 + sb * 64 + scc];
        const float uv = *su_p;                // u[b][t][c]
        const float th = tanhf(uv + mm);
        hz += DT * (th - gam * hy - ep * hz);
        hy += DT * hz;
        *su_p = hy;                            // all_states[b][t][c]
        su_p += H;

        // --- 4. publish hy_{t+1} slice (double-buffered), barrier bump ---
        float* dst = wshy + (((t + 1) & 1) ? (size_t)(B * H) : 0)
                     + (size_t)(b0 + sb) * H + sc;
        __hip_atomic_store(dst, hy, __ATOMIC_RELAXED, __HIP_MEMORY_SCOPE_AGENT);
        if (t == L - 1) hyfin[(size_t)(b0 + sb) * H + sc] = hy;
        __syncthreads();                       // drains vmcnt: slice stores complete
        if (tid == 0)
            __hip_atomic_fetch_add(myctr, 1u, __ATOMIC_RELEASE, __HIP_MEMORY_SCOPE_AGENT);
    }
}

extern "C" void kernel_launch(void* const* d_in, const int* in_sizes, int n_in,
                              void* d_out, int out_size, void* d_ws, size_t ws_size,
                              hipStream_t stream) {
    const float* x     = (const float*)d_in[0];
    const float* x2h   = (const float*)d_in[1];
    const float* h2h   = (const float*)d_in[2];
    const float* bias  = (const float*)d_in[3];
    const float* gamma = (const float*)d_in[4];
    const float* epsv  = (const float*)d_in[5];
    float* states = (float*)d_out;                         // (B, L, H) f32
    float* hyfin  = states + (size_t)B * L * H;            // (B, H) f32

    unsigned* ctr = (unsigned*)d_ws;                       // 8 counters, 128B stride
    float* wshy = (float*)d_ws + 1024;                     // 2 x (B*H) hy exchange bufs

    hipMemsetAsync(d_ws, 0, 4096, stream);                 // zero barrier counters
    dim3 g1(B * L / 64, H / 64);                           // (1024, 8)
    k_ugemm<<<g1, 256, 0, stream>>>(x, x2h, bias, states);
    k_scan<<<64, 512, 0, stream>>>(states, h2h, gamma, epsv, ctr, wshy, hyfin);
}

// Round 2
// 4164.491 us; speedup vs baseline: 1.8149x; 1.8149x over previous
//
#include <hip/hip_runtime.h>

#define DT 0.042f
constexpr int B = 64, L = 1024, I = 128, H = 512;

// scan decomposition: 16 batch-groups x 16 column-slices = 256 blocks (<= 256 CUs,
// all co-resident at any packing; 80 KiB LDS/block).
constexpr int NG = 16;          // batch groups
constexpr int NS = 16;          // column slices (group radius = 16 blocks)
constexpr int GB = B / NG;      // 4 batches per group
constexpr int SC = H / NS;      // 32 cols per slice

// ---------------------------------------------------------------------------
// Kernel 1: u = x @ x2h + bias -> staged into the all_states region of d_out
// ---------------------------------------------------------------------------
__global__ __launch_bounds__(256) void k_ugemm(const float* __restrict__ x,
                                               const float* __restrict__ w,
                                               const float* __restrict__ bias,
                                               float* __restrict__ u) {
    __shared__ __align__(16) float a_s[64][132];
    __shared__ __align__(16) float b_s[128][68];
    const int tx = threadIdx.x & 15;
    const int ty = threadIdx.x >> 4;
    const int row0 = blockIdx.x * 64;
    const int col0 = blockIdx.y * 64;

    for (int i = threadIdx.x; i < 64 * 32; i += 256) {
        int r = i >> 5, c4 = (i & 31) << 2;
        *(float4*)&a_s[r][c4] = *(const float4*)(x + (size_t)(row0 + r) * I + c4);
    }
    for (int i = threadIdx.x; i < 128 * 16; i += 256) {
        int k = i >> 4, c4 = (i & 15) << 2;
        *(float4*)&b_s[k][c4] = *(const float4*)(w + (size_t)k * H + col0 + c4);
    }
    __syncthreads();

    float acc[4][4] = {};
    for (int k = 0; k < I; k += 4) {
        float a4[4][4], b4[4][4];
        #pragma unroll
        for (int i = 0; i < 4; ++i) *(float4*)a4[i] = *(const float4*)&a_s[ty * 4 + i][k];
        #pragma unroll
        for (int kk = 0; kk < 4; ++kk) *(float4*)b4[kk] = *(const float4*)&b_s[k + kk][tx * 4];
        #pragma unroll
        for (int i = 0; i < 4; ++i)
            #pragma unroll
            for (int kk = 0; kk < 4; ++kk)
                #pragma unroll
                for (int j = 0; j < 4; ++j)
                    acc[i][j] += a4[i][kk] * b4[kk][j];
    }
    float4 bv = *(const float4*)&bias[col0 + tx * 4];
    #pragma unroll
    for (int i = 0; i < 4; ++i) {
        size_t r = (size_t)(row0 + ty * 4 + i);
        float4 o;
        o.x = acc[i][0] + bv.x; o.y = acc[i][1] + bv.y;
        o.z = acc[i][2] + bv.z; o.w = acc[i][3] + bv.w;
        *(float4*)&u[r * H + col0 + tx * 4] = o;
    }
}

// ---------------------------------------------------------------------------
// Kernel 2: the scan.
// Per step: relaxed poll on group counter -> one agent-acquire fence (wave 0)
// -> plain float4 loads of hy (8 KB) -> LDS matmul partials -> k-reduction +
// state update (128 threads) -> 128 relaxed-atomic WT dword publishes ->
// barrier (vmcnt drain == completion at L3) -> relaxed fetch_add.
// Double-buffered wshy; counter>=NS*t implies peers finished reading the
// buffer we overwrite (their release-chain add follows their reads).
// ---------------------------------------------------------------------------
__global__ __launch_bounds__(512) void k_scan(float* __restrict__ su,
                                              const float* __restrict__ h2h,
                                              const float* __restrict__ gamma,
                                              const float* __restrict__ epsv,
                                              unsigned* __restrict__ ctr,
                                              float* __restrict__ wshy,
                                              float* __restrict__ hyfin) {
    __shared__ __align__(16) float h2h_s[H * SC];       // [k][cc]   64 KiB
    __shared__ __align__(16) float hy_s[GB * H];        // [b][k]     8 KiB
    __shared__ __align__(16) float red[16 * GB * SC];   // [kc][b][cc] 8 KiB
    const int tid = threadIdx.x;
    const int g = blockIdx.x & 15;    // group: members stride-16 -> same XCD (heuristic)
    const int s = blockIdx.x >> 4;    // column slice
    const int b0 = g * GB, c0 = s * SC;

    for (int i = tid; i < H * (SC / 4); i += 512) {     // h2h slice, float4
        int k = i >> 3, c4 = (i & 7) << 2;
        *(float4*)&h2h_s[k * SC + c4] = *(const float4*)(h2h + (size_t)k * H + c0 + c4);
    }

    const int cc = tid & 31, kc = tid >> 5;             // compute map (32 cols x 16 k-chunks)
    const int scc = tid & 31, sb = (tid >> 5) & 3;      // state map (tid < 128)
    const int sc = c0 + scc;
    float gam = 0.f, ep = 0.f;
    float* su_p = nullptr;
    if (tid < 128) {
        gam = gamma[sc]; ep = epsv[sc];
        su_p = su + (size_t)(b0 + sb) * L * H + sc;
    }
    unsigned* myctr = ctr + g * 32;                     // 128B-strided counters
    float hy = 0.f, hz = 0.f;
    __syncthreads();

    for (int t = 0; t < L; ++t) {
        float uval = 0.f;
        if (tid < 128) uval = *su_p;                    // u[t] prefetch (hides under sync)

        if (t > 0) {
            if (tid == 0) {
                const unsigned target = (unsigned)(NS * t);
                while (__hip_atomic_load(myctr, __ATOMIC_RELAXED,
                                         __HIP_MEMORY_SCOPE_AGENT) < target) {}
            }
            __syncthreads();                            // (a) data-ready known
            if (tid < 64) __builtin_amdgcn_fence(__ATOMIC_ACQUIRE, "agent");
            __syncthreads();                            // (b) L1/L2 invalidated
            const float* src = wshy + ((t & 1) ? (size_t)(B * H) : 0) + (size_t)b0 * H;
            *(float4*)&hy_s[tid * 4] = *(const float4*)&src[tid * 4];   // 8 KB, coalesced
        } else {
            *(float4*)&hy_s[tid * 4] = float4{0.f, 0.f, 0.f, 0.f};
        }
        __syncthreads();                                // (c) hy_s ready

        // partial matmul: acc[b] = sum_{k in chunk} hy[b][k] * h2h[k][cc]
        float acc[GB] = {};
        const int k0 = kc * 32;
        #pragma unroll
        for (int kk = 0; kk < 32; kk += 4) {
            const int k = k0 + kk;
            const float h0 = h2h_s[(k + 0) * SC + cc], h1 = h2h_s[(k + 1) * SC + cc];
            const float h2v = h2h_s[(k + 2) * SC + cc], h3 = h2h_s[(k + 3) * SC + cc];
            #pragma unroll
            for (int b = 0; b < GB; ++b) {
                const float4 hv = *(const float4*)&hy_s[b * H + k];  // half-wave broadcast
                acc[b] += hv.x * h0 + hv.y * h1 + hv.z * h2v + hv.w * h3;
            }
        }
        #pragma unroll
        for (int b = 0; b < GB; ++b) red[kc * (GB * SC) + b * SC + cc] = acc[b];
        __syncthreads();                                // (d) partials ready

        if (tid < 128) {
            float mm = 0.f;
            #pragma unroll
            for (int q = 0; q < 16; ++q) mm += red[q * (GB * SC) + sb * SC + scc];
            const float th = tanhf(uval + mm);
            hz += DT * (th - gam * hy - ep * hz);
            hy += DT * hz;
            *su_p = hy;                                 // all_states[b][t][c]
            su_p += H;
            float* dst = wshy + (((t + 1) & 1) ? (size_t)(B * H) : 0)
                         + (size_t)(b0 + sb) * H + sc;
            __hip_atomic_store(dst, hy, __ATOMIC_RELAXED, __HIP_MEMORY_SCOPE_AGENT);
            if (t == L - 1) hyfin[(size_t)(b0 + sb) * H + sc] = hy;
        }
        __syncthreads();                                // (e) vmcnt drain: publishes at L3
        if (tid == 0)
            __hip_atomic_fetch_add(myctr, 1u, __ATOMIC_RELAXED, __HIP_MEMORY_SCOPE_AGENT);
    }
}

extern "C" void kernel_launch(void* const* d_in, const int* in_sizes, int n_in,
                              void* d_out, int out_size, void* d_ws, size_t ws_size,
                              hipStream_t stream) {
    const float* x     = (const float*)d_in[0];
    const float* x2h   = (const float*)d_in[1];
    const float* h2h   = (const float*)d_in[2];
    const float* bias  = (const float*)d_in[3];
    const float* gamma = (const float*)d_in[4];
    const float* epsv  = (const float*)d_in[5];
    float* states = (float*)d_out;                      // (B, L, H)
    float* hyfin  = states + (size_t)B * L * H;         // (B, H)

    unsigned* ctr = (unsigned*)d_ws;                    // 16 counters, 128B stride
    float* wshy = (float*)d_ws + 1024;                  // 2 x (B*H) exchange buffers

    hipMemsetAsync(d_ws, 0, 4096, stream);              // zero counters
    dim3 g1(B * L / 64, H / 64);
    k_ugemm<<<g1, 256, 0, stream>>>(x, x2h, bias, states);
    k_scan<<<NG * NS, 512, 0, stream>>>(states, h2h, gamma, epsv, ctr, wshy, hyfin);
}

// Round 3
// 2585.002 us; speedup vs baseline: 2.9238x; 1.6110x over previous
//
#include <hip/hip_runtime.h>

#define DT 0.042f
constexpr int B = 64, L = 1024, I = 128, H = 512;

// scan decomposition: 16 batch-groups x 16 column-slices = 256 blocks (<= 256 CUs,
// all co-resident at any packing; 80 KiB LDS/block).
constexpr int NG = 16;          // batch groups
constexpr int NS = 16;          // column slices
constexpr int GB = B / NG;      // 4 batches per group
constexpr int SC = H / NS;      // 32 cols per slice

// ---------------------------------------------------------------------------
// Kernel 1: u = x @ x2h + bias -> staged into the all_states region of d_out
// ---------------------------------------------------------------------------
__global__ __launch_bounds__(256) void k_ugemm(const float* __restrict__ x,
                                               const float* __restrict__ w,
                                               const float* __restrict__ bias,
                                               float* __restrict__ u) {
    __shared__ __align__(16) float a_s[64][132];
    __shared__ __align__(16) float b_s[128][68];
    const int tx = threadIdx.x & 15;
    const int ty = threadIdx.x >> 4;
    const int row0 = blockIdx.x * 64;
    const int col0 = blockIdx.y * 64;

    for (int i = threadIdx.x; i < 64 * 32; i += 256) {
        int r = i >> 5, c4 = (i & 31) << 2;
        *(float4*)&a_s[r][c4] = *(const float4*)(x + (size_t)(row0 + r) * I + c4);
    }
    for (int i = threadIdx.x; i < 128 * 16; i += 256) {
        int k = i >> 4, c4 = (i & 15) << 2;
        *(float4*)&b_s[k][c4] = *(const float4*)(w + (size_t)k * H + col0 + c4);
    }
    __syncthreads();

    float acc[4][4] = {};
    for (int k = 0; k < I; k += 4) {
        float a4[4][4], b4[4][4];
        #pragma unroll
        for (int i = 0; i < 4; ++i) *(float4*)a4[i] = *(const float4*)&a_s[ty * 4 + i][k];
        #pragma unroll
        for (int kk = 0; kk < 4; ++kk) *(float4*)b4[kk] = *(const float4*)&b_s[k + kk][tx * 4];
        #pragma unroll
        for (int i = 0; i < 4; ++i)
            #pragma unroll
            for (int kk = 0; kk < 4; ++kk)
                #pragma unroll
                for (int j = 0; j < 4; ++j)
                    acc[i][j] += a4[i][kk] * b4[kk][j];
    }
    float4 bv = *(const float4*)&bias[col0 + tx * 4];
    #pragma unroll
    for (int i = 0; i < 4; ++i) {
        size_t r = (size_t)(row0 + ty * 4 + i);
        float4 o;
        o.x = acc[i][0] + bv.x; o.y = acc[i][1] + bv.y;
        o.z = acc[i][2] + bv.z; o.w = acc[i][3] + bv.w;
        *(float4*)&u[r * H + col0 + tx * 4] = o;
    }
}

// ---------------------------------------------------------------------------
// Kernel 2: the scan, dataflow-synchronized.
// Exchange words are (tag<<32 | float_bits) qwords in d_ws, double-buffered by
// step parity. Publish: relaxed agent-scope 64-bit atomic store (goes to L3
// coherence point). Consume: each thread polls ITS OWN 4 qwords (all within one
// producer's slice) with relaxed agent-scope atomic loads until tag==t.
// No counter, no RMW, no fence, no separate data load: data arrival IS the
// synchronization. Buffer-reuse safety: a block publishes t+1 into slot
// (t+1)&1 (holding t-1) only after it consumed ALL of t, which every peer
// could only publish after consuming t-1 -> slot is dead. Same-thread
// same-address store ordering gives monotone tags per word.
// ---------------------------------------------------------------------------
__global__ __launch_bounds__(512) void k_scan(float* __restrict__ su,
                                              const float* __restrict__ h2h,
                                              const float* __restrict__ gamma,
                                              const float* __restrict__ epsv,
                                              unsigned long long* __restrict__ wsq,
                                              float* __restrict__ hyfin) {
    __shared__ __align__(16) float h2h_s[H * SC];       // [k][cc]   64 KiB
    __shared__ __align__(16) float hy_s[GB * H];        // [b][k]     8 KiB
    __shared__ __align__(16) float red[16 * GB * SC];   // [kc][b][cc] 8 KiB
    const int tid = threadIdx.x;
    const int g = blockIdx.x & 15;    // group members stride-16 -> same XCD (perf heuristic)
    const int s = blockIdx.x >> 4;    // column slice
    const int b0 = g * GB, c0 = s * SC;

    for (int i = tid; i < H * (SC / 4); i += 512) {     // h2h slice, float4
        int k = i >> 3, c4 = (i & 7) << 2;
        *(float4*)&h2h_s[k * SC + c4] = *(const float4*)(h2h + (size_t)k * H + c0 + c4);
    }

    const int cc = tid & 31, kc = tid >> 5;             // compute map (32 cols x 16 k-chunks)
    const int scc = tid & 31, sb = (tid >> 5) & 3;      // state map (tid < 128)
    const int sc = c0 + scc;
    float gam = 0.f, ep = 0.f;
    float* su_p = nullptr;
    if (tid < 128) {
        gam = gamma[sc]; ep = epsv[sc];
        su_p = su + (size_t)(b0 + sb) * L * H + sc;
    }
    // poll sources: this thread's 4 consecutive qwords of the group's hy region
    unsigned long long* srcA = wsq + (size_t)b0 * H + (size_t)tid * 4;              // buf 0
    unsigned long long* srcB = wsq + (size_t)B * H + (size_t)b0 * H + (size_t)tid * 4;  // buf 1
    unsigned long long* dstA = wsq + (size_t)(b0 + sb) * H + sc;
    unsigned long long* dstB = wsq + (size_t)B * H + (size_t)(b0 + sb) * H + sc;

    float hy = 0.f, hz = 0.f;
    __syncthreads();

    for (int t = 0; t < L; ++t) {
        float uval = 0.f;
        if (tid < 128) uval = *su_p;                    // u[t] prefetch (plain, cached)

        if (t > 0) {
            unsigned long long* src = (t & 1) ? srcB : srcA;
            unsigned long long w[4];
            #pragma unroll
            for (int j = 0; j < 4; ++j)                 // 4 loads in flight in parallel
                w[j] = __hip_atomic_load(src + j, __ATOMIC_RELAXED, __HIP_MEMORY_SCOPE_AGENT);
            const unsigned tg = (unsigned)t;
            bool done = false;
            while (!done) {                             // re-poll only stale words
                done = true;
                #pragma unroll
                for (int j = 0; j < 4; ++j)
                    if ((unsigned)(w[j] >> 32) != tg) {
                        w[j] = __hip_atomic_load(src + j, __ATOMIC_RELAXED,
                                                 __HIP_MEMORY_SCOPE_AGENT);
                        done = false;
                    }
            }
            #pragma unroll
            for (int j = 0; j < 4; ++j)
                hy_s[tid * 4 + j] = __uint_as_float((unsigned)w[j]);
        } else {
            *(float4*)&hy_s[tid * 4] = float4{0.f, 0.f, 0.f, 0.f};
        }
        __syncthreads();                                // (1) hy_s ready

        // partial matmul: acc[b] = sum_{k in chunk} hy[b][k] * h2h[k][cc]
        float acc[GB] = {};
        const int k0 = kc * 32;
        #pragma unroll
        for (int kk = 0; kk < 32; kk += 4) {
            const int k = k0 + kk;
            const float h0 = h2h_s[(k + 0) * SC + cc], h1 = h2h_s[(k + 1) * SC + cc];
            const float h2v = h2h_s[(k + 2) * SC + cc], h3 = h2h_s[(k + 3) * SC + cc];
            #pragma unroll
            for (int b = 0; b < GB; ++b) {
                const float4 hv = *(const float4*)&hy_s[b * H + k];  // half-wave broadcast
                acc[b] += hv.x * h0 + hv.y * h1 + hv.z * h2v + hv.w * h3;
            }
        }
        #pragma unroll
        for (int b = 0; b < GB; ++b) red[kc * (GB * SC) + b * SC + cc] = acc[b];
        __syncthreads();                                // (2) partials ready

        if (tid < 128) {
            float mm = 0.f;
            #pragma unroll
            for (int q = 0; q < 16; ++q) mm += red[q * (GB * SC) + sb * SC + scc];
            const float xx = uval + mm;
            const float cxv = fminf(fmaxf(xx, -10.f), 10.f);   // tanh via exp, clamped
            const float e2 = __expf(2.f * cxv);
            const float th = (e2 - 1.f) / (e2 + 1.f);
            hz += DT * (th - gam * hy - ep * hz);
            hy += DT * hz;
            *su_p = hy;                                 // all_states[b][t][c]
            su_p += H;
            const unsigned long long w =
                ((unsigned long long)(unsigned)(t + 1) << 32) | __float_as_uint(hy);
            __hip_atomic_store(((t + 1) & 1) ? dstB : dstA, w,
                               __ATOMIC_RELAXED, __HIP_MEMORY_SCOPE_AGENT);
            if (t == L - 1) hyfin[(size_t)(b0 + sb) * H + sc] = hy;
        }
        __syncthreads();                                // (3) red/hy_s safe to overwrite
    }
}

extern "C" void kernel_launch(void* const* d_in, const int* in_sizes, int n_in,
                              void* d_out, int out_size, void* d_ws, size_t ws_size,
                              hipStream_t stream) {
    const float* x     = (const float*)d_in[0];
    const float* x2h   = (const float*)d_in[1];
    const float* h2h   = (const float*)d_in[2];
    const float* bias  = (const float*)d_in[3];
    const float* gamma = (const float*)d_in[4];
    const float* epsv  = (const float*)d_in[5];
    float* states = (float*)d_out;                      // (B, L, H)
    float* hyfin  = states + (size_t)B * L * H;         // (B, H)

    unsigned long long* wsq = (unsigned long long*)d_ws;  // 2 x (B*H) tagged qwords

    hipMemsetAsync(d_ws, 0, 2ull * B * H * 8, stream);  // tag 0 != any awaited t>=1
    dim3 g1(B * L / 64, H / 64);
    k_ugemm<<<g1, 256, 0, stream>>>(x, x2h, bias, states);
    k_scan<<<NG * NS, 512, 0, stream>>>(states, h2h, gamma, epsv, wsq, hyfin);
}